// Round 7
// baseline (334.085 us; speedup 1.0000x reference)
//
#include <hip/hip_runtime.h>
#include <hip/hip_bf16.h>
#include <cstdint>

typedef __bf16 bf16x8 __attribute__((ext_vector_type(8)));
typedef float f32x4 __attribute__((ext_vector_type(4)));
typedef float f32x16 __attribute__((ext_vector_type(16)));

#define MFMA16(a, b, c) __builtin_amdgcn_mfma_f32_16x16x32_bf16(a, b, c, 0, 0, 0)
#define MFMA32(a, b, c) __builtin_amdgcn_mfma_f32_32x32x16_bf16(a, b, c, 0, 0, 0)

__device__ __forceinline__ void gload_lds16(const void* g, void* l) {
  __builtin_amdgcn_global_load_lds(
      (const __attribute__((address_space(1))) unsigned int*)g,
      (__attribute__((address_space(3))) unsigned int*)l, 16, 0, 0);
}

__device__ __forceinline__ unsigned short f2bf(float x) {
  union { float f; uint32_t u; } v; v.f = x;
  uint32_t r = v.u + 0x7fff + ((v.u >> 16) & 1);
  return (unsigned short)(r >> 16);
}
__device__ __forceinline__ float bf2f(unsigned short h) {
  union { float f; uint32_t u; } v; v.u = ((uint32_t)h) << 16;
  return v.f;
}
__device__ __forceinline__ f32x16 fzero16() {
  f32x16 v;
#pragma unroll
  for (int i = 0; i < 16; ++i) v[i] = 0.f;
  return v;
}

// ---------------- K1a: hidden_states -> bf16 ----------------
__global__ __launch_bounds__(256) void k_split(const float* __restrict__ x,
                                               unsigned short* __restrict__ hi, int n4) {
  int i = blockIdx.x * blockDim.x + threadIdx.x;
  if (i >= n4) return;
  float4 v = ((const float4*)x)[i];
  ushort4 h;
  h.x = f2bf(v.x); h.y = f2bf(v.y); h.z = f2bf(v.z); h.w = f2bf(v.w);
  ((ushort4*)hi)[i] = h;
}

// ------------ K1b: transpose weights -> bf16 (fused, z selects W) ------------
__global__ __launch_bounds__(256) void k_wsplit(
    const float* __restrict__ Wq, const float* __restrict__ Wk,
    const float* __restrict__ Wv, const float* __restrict__ Wo,
    unsigned short* __restrict__ WtqH, unsigned short* __restrict__ WtkH,
    unsigned short* __restrict__ WtvH, unsigned short* __restrict__ WtoH) {
  const int z = blockIdx.z;
  const float* W = (z == 0) ? Wq : (z == 1) ? Wk : (z == 2) ? Wv : Wo;
  unsigned short* WtH = (z == 0) ? WtqH : (z == 1) ? WtkH : (z == 2) ? WtvH : WtoH;
  __shared__ float tile[32][33];
  const int bx = blockIdx.x, by = blockIdx.y;
  const int tx = threadIdx.x & 31, ty = threadIdx.x >> 5;
#pragma unroll
  for (int i = 0; i < 4; ++i)
    tile[ty + i * 8][tx] = W[(size_t)(by * 32 + ty + i * 8) * 1024 + bx * 32 + tx];
  __syncthreads();
#pragma unroll
  for (int i = 0; i < 4; ++i) {
    float v = tile[tx][ty + i * 8];
    WtH[(size_t)(bx * 32 + ty + i * 8) * 1024 + by * 32 + tx] = f2bf(v);
  }
}

// ---------------- K2: QKV GEMM, plain bf16, global_load_lds staging ----------------
__global__ __launch_bounds__(256, 2) void k_qkv(
    const unsigned short* __restrict__ hsH,
    const unsigned short* __restrict__ WqH, const unsigned short* __restrict__ WkH,
    const unsigned short* __restrict__ WvH, const float* __restrict__ freqs,
    unsigned short* __restrict__ qB, unsigned short* __restrict__ kB,
    unsigned short* __restrict__ vB) {
  __shared__ unsigned short Ah[128 * 32], Bh[128 * 32];  // 8KB each, 64B rows
  const int tid = threadIdx.x;
  const int bm = blockIdx.y, bn = blockIdx.x;
  const int w = bn >> 3;           // 0=q 1=k 2=v
  const int n0 = (bn & 7) * 128;
  const unsigned short* WH = (w == 0) ? WqH : (w == 1) ? WkH : WvH;
  const int lane = tid & 63, wave = tid >> 6;
  const int wm = (wave & 1) * 64, wn = (wave >> 1) * 64;
  const int l15 = lane & 15, lq = lane >> 4;

  f32x4 acc[4][4];
#pragma unroll
  for (int i = 0; i < 4; i++)
#pragma unroll
    for (int j = 0; j < 4; j++) acc[i][j] = (f32x4){0.f, 0.f, 0.f, 0.f};

  const char* baseA = (const char*)hsH + (size_t)(bm * 128) * 2048;
  const char* baseB = (const char*)WH + (size_t)n0 * 2048;
  const int off0 = tid << 4, row0 = off0 >> 6, seg0 = off0 & 63;
  const int off1 = (tid + 256) << 4, row1 = off1 >> 6, seg1 = off1 & 63;

  for (int k0 = 0; k0 < 1024; k0 += 32) {
    __syncthreads();
    gload_lds16(baseA + (size_t)row0 * 2048 + k0 * 2 + seg0, (char*)Ah + wave * 1024);
    gload_lds16(baseB + (size_t)row0 * 2048 + k0 * 2 + seg0, (char*)Bh + wave * 1024);
    gload_lds16(baseA + (size_t)row1 * 2048 + k0 * 2 + seg1,
                (char*)Ah + 4096 + wave * 1024);
    gload_lds16(baseB + (size_t)row1 * 2048 + k0 * 2 + seg1,
                (char*)Bh + 4096 + wave * 1024);
    __syncthreads();
    bf16x8 ah[4], bh[4];
#pragma unroll
    for (int i = 0; i < 4; ++i) {
      ah[i] = *(const bf16x8*)&Ah[(wm + i * 16 + l15) * 32 + lq * 8];
      bh[i] = *(const bf16x8*)&Bh[(wn + i * 16 + l15) * 32 + lq * 8];
    }
#pragma unroll
    for (int i = 0; i < 4; ++i)
#pragma unroll
      for (int j = 0; j < 4; ++j) acc[i][j] = MFMA16(ah[i], bh[j], acc[i][j]);
  }

  // epilogue: C/D layout col=lane&15, row=(lane>>4)*4+r. RoPE for q,k. V transposed.
  unsigned short* dst = (w == 0) ? qB : (w == 1) ? kB : vB;
#pragma unroll
  for (int i = 0; i < 4; ++i) {
#pragma unroll
    for (int j = 0; j < 4; ++j) {
      int colw = n0 + wn + j * 16 + l15;
      int h = colw >> 6, d = colw & 63;
#pragma unroll
      for (int r = 0; r < 4; ++r) {
        int rowg = bm * 128 + wm + i * 16 + lq * 4 + r;
        int s = rowg & 2047, b = rowg >> 11;
        float val = acc[i][j][r];
        if (w < 2) {
          float partner = __shfl_xor(val, 1);
          int jj = d >> 1;
          float cs = freqs[(s * 32 + jj) * 2 + 0];
          float sn = freqs[(s * 32 + jj) * 2 + 1];
          float res = (d & 1) ? (partner * sn + val * cs) : (val * cs - partner * sn);
          dst[(((size_t)(b * 16 + h)) * 2048 + s) * 64 + d] = f2bf(res);
        } else {
          dst[(((size_t)(b * 16 + h)) * 64 + d) * 2048 + s] = f2bf(val);  // vB[bh][d][s]
        }
      }
    }
  }
}

// ------- K3: attention, 64 q/wave, chunk x sub split, NO LDS (shfl transpose) -------
// blockIdx.z = chunk*2+sub (512 keys each). exp2 has no max-shift, so unnormalized
// partials are summable: write raw bf16 o + fp32 rowsum; k_comb normalizes/combines.
// P transform C->B layout: lanes l and l^32 hold complementary key quads; one
// shfl_xor(32) per packed pair + cndmask-select builds the B-frag in-register.
__global__ __launch_bounds__(256, 3) void k_attn(
    const unsigned short* __restrict__ qB, const unsigned short* __restrict__ kB,
    const unsigned short* __restrict__ vB,
    unsigned short* __restrict__ cP, float* __restrict__ rsW) {
  const int tid = threadIdx.x, lane = tid & 63, wave = tid >> 6;
  const int l31 = lane & 31, lh = lane >> 5;
  const int bh = blockIdx.y;
  const int z = blockIdx.z;               // 0..3: chunk = z>>1, sub = z&1
  const int key00 = (z >> 1) * 1024 + (z & 1) * 512;
  const int q0 = blockIdx.x * 256 + wave * 64;
  const size_t base = (size_t)bh * 2048 * 64;
  const float sc = 0.125f * 1.44269504089f;  // scale * log2(e)

  // Q B-frags: lane n=l31 -> query q0+qt*32+l31, k=ks*16+lh*8
  bf16x8 qf[2][4];
#pragma unroll
  for (int qt = 0; qt < 2; ++qt)
#pragma unroll
    for (int ks = 0; ks < 4; ++ks)
      qf[qt][ks] = *(const bf16x8*)(qB + base + (size_t)(q0 + qt * 32 + l31) * 64 +
                                    ks * 16 + lh * 8);

  const unsigned short* kp = kB + base + (size_t)key00 * 64 + l31 * 64 + lh * 8;
  const unsigned short* vp = vB + base + l31 * 2048 + key00 + lh * 8;

  f32x16 o[2][2];  // [dt][qt]
#pragma unroll
  for (int a = 0; a < 2; ++a)
#pragma unroll
    for (int bq = 0; bq < 2; ++bq) o[a][bq] = fzero16();
  float rsum[2] = {0.f, 0.f};

  for (int kb = 0; kb < 8; ++kb) {
    bf16x8 vf[2][4];
#pragma unroll
    for (int dt = 0; dt < 2; ++dt)
#pragma unroll
      for (int ks = 0; ks < 4; ++ks)
        vf[dt][ks] = *(const bf16x8*)(vp + dt * 65536 + ks * 16);

#pragma unroll
    for (int mt = 0; mt < 2; ++mt) {
      bf16x8 kf[4];
#pragma unroll
      for (int ks = 0; ks < 4; ++ks)
        kf[ks] = *(const bf16x8*)(kp + mt * 2048 + ks * 16);
      f32x16 s0 = fzero16(), s1 = fzero16();
#pragma unroll
      for (int ks = 0; ks < 4; ++ks) {
        s0 = MFMA32(kf[ks], qf[0][ks], s0);
        s1 = MFMA32(kf[ks], qf[1][ks], s1);
      }
#pragma unroll
      for (int qt = 0; qt < 2; ++qt) {
        const f32x16& sv = qt ? s1 : s0;
        float ps[16];
        float rs = 0.f;
#pragma unroll
        for (int r = 0; r < 16; ++r) {
          ps[r] = __builtin_exp2f(sv[r] * sc);
          rs += ps[r];
        }
        rsum[qt] += rs;
        // pack adjacent-key pairs (regs 2p,2p+1) and exchange with lane^32
        unsigned own[8], part[8];
#pragma unroll
        for (int p = 0; p < 8; ++p) {
          union { unsigned u; __bf16 h2[2]; } pk;
          pk.h2[0] = (__bf16)ps[2 * p];
          pk.h2[1] = (__bf16)ps[2 * p + 1];
          own[p] = pk.u;
        }
#pragma unroll
        for (int p = 0; p < 8; ++p)
          part[p] = (unsigned)__shfl_xor((int)own[p], 32);
        // assemble B-frags for the two 16-key groups of this mt, run PV
#pragma unroll
        for (int ksl = 0; ksl < 2; ++ksl) {
          union { unsigned u[4]; bf16x8 v; } pf;
          pf.u[0] = lh ? part[4 * ksl + 2] : own[4 * ksl];
          pf.u[1] = lh ? part[4 * ksl + 3] : own[4 * ksl + 1];
          pf.u[2] = lh ? own[4 * ksl + 2] : part[4 * ksl];
          pf.u[3] = lh ? own[4 * ksl + 3] : part[4 * ksl + 1];
          const int gks = mt * 2 + ksl;
          o[0][qt] = MFMA32(vf[0][gks], pf.v, o[0][qt]);
          o[1][qt] = MFMA32(vf[1][gks], pf.v, o[1][qt]);
        }
      }
    }
    kp += 4096;  // 64 keys * 64 elems
    vp += 64;    // 64 keys
  }

  // epilogue: write raw bf16 partial o + fp32 rowsum. O^T: d=dt*32+4*lh+8*g+t,
  // q=qt*32+l31.
  unsigned short* cB = cP + (size_t)z * (4096 * 1024);
  const int b = bh >> 4, h = bh & 15;
#pragma unroll
  for (int qt = 0; qt < 2; ++qt) {
    float lsum = rsum[qt] + __shfl_xor(rsum[qt], 32);
    int s = q0 + qt * 32 + l31;
    if (lh == 0) rsW[((size_t)z * 32 + bh) * 2048 + s] = lsum;
#pragma unroll
    for (int dt = 0; dt < 2; ++dt)
#pragma unroll
      for (int g = 0; g < 4; ++g) {
        int d = dt * 32 + 4 * lh + 8 * g;
        size_t idx = ((size_t)(b * 2048 + s)) * 1024 + h * 64 + d;
        ushort4 hv;
#pragma unroll
        for (int t = 0; t < 4; ++t)
          ((unsigned short*)&hv)[t] = f2bf(o[dt][qt][g * 4 + t]);
        *(ushort4*)(cB + idx) = hv;
      }
  }
}

// ------- K3b: combine: attnB = (z0+z1)/(l0+l1) + (z2+z3)/(l2+l3), bf16 -------
__global__ __launch_bounds__(256) void k_comb(const unsigned short* __restrict__ cP,
                                              const float* __restrict__ rsW,
                                              unsigned short* __restrict__ outB,
                                              int n8) {
  int i = blockIdx.x * blockDim.x + threadIdx.x;
  if (i >= n8) return;
  const size_t MD = (size_t)4096 * 1024;
  int flat = i * 8;
  int col = flat & 1023;
  int srow = (flat >> 10) & 2047;
  int b = flat >> 21;
  int bh = b * 16 + (col >> 6);
  float l0 = rsW[(size_t)(0 * 32 + bh) * 2048 + srow] +
             rsW[(size_t)(1 * 32 + bh) * 2048 + srow];
  float l1 = rsW[(size_t)(2 * 32 + bh) * 2048 + srow] +
             rsW[(size_t)(3 * 32 + bh) * 2048 + srow];
  float i0 = 1.f / l0, i1 = 1.f / l1;
  uint4 a0 = ((const uint4*)cP)[i];
  uint4 a1 = ((const uint4*)(cP + MD))[i];
  uint4 a2 = ((const uint4*)(cP + 2 * MD))[i];
  uint4 a3 = ((const uint4*)(cP + 3 * MD))[i];
  uint4 r;
  const unsigned short* p0 = (const unsigned short*)&a0;
  const unsigned short* p1 = (const unsigned short*)&a1;
  const unsigned short* p2 = (const unsigned short*)&a2;
  const unsigned short* p3 = (const unsigned short*)&a3;
  unsigned short* pr = (unsigned short*)&r;
#pragma unroll
  for (int j = 0; j < 8; ++j)
    pr[j] = f2bf((bf2f(p0[j]) + bf2f(p1[j])) * i0 +
                 (bf2f(p2[j]) + bf2f(p3[j])) * i1);
  ((uint4*)outB)[i] = r;
}

// ---------------- K4: output projection, plain bf16, fp32 store ----------------
__global__ __launch_bounds__(256, 2) void k_out(const unsigned short* __restrict__ A,
                                                const unsigned short* __restrict__ B,
                                                float* __restrict__ out) {
  __shared__ unsigned short Ah[128 * 32], Bh[128 * 32];
  const int tid = threadIdx.x;
  const int bm = blockIdx.y, n0 = blockIdx.x * 128;
  const int lane = tid & 63, wave = tid >> 6;
  const int wm = (wave & 1) * 64, wn = (wave >> 1) * 64;
  const int l15 = lane & 15, lq = lane >> 4;

  f32x4 acc[4][4];
#pragma unroll
  for (int i = 0; i < 4; i++)
#pragma unroll
    for (int j = 0; j < 4; j++) acc[i][j] = (f32x4){0.f, 0.f, 0.f, 0.f};

  const char* baseA = (const char*)A + (size_t)(bm * 128) * 2048;
  const char* baseB = (const char*)B + (size_t)n0 * 2048;
  const int off0 = tid << 4, row0 = off0 >> 6, seg0 = off0 & 63;
  const int off1 = (tid + 256) << 4, row1 = off1 >> 6, seg1 = off1 & 63;

  for (int k0 = 0; k0 < 1024; k0 += 32) {
    __syncthreads();
    gload_lds16(baseA + (size_t)row0 * 2048 + k0 * 2 + seg0, (char*)Ah + wave * 1024);
    gload_lds16(baseB + (size_t)row0 * 2048 + k0 * 2 + seg0, (char*)Bh + wave * 1024);
    gload_lds16(baseA + (size_t)row1 * 2048 + k0 * 2 + seg1,
                (char*)Ah + 4096 + wave * 1024);
    gload_lds16(baseB + (size_t)row1 * 2048 + k0 * 2 + seg1,
                (char*)Bh + 4096 + wave * 1024);
    __syncthreads();
    bf16x8 ah[4], bh[4];
#pragma unroll
    for (int i = 0; i < 4; ++i) {
      ah[i] = *(const bf16x8*)&Ah[(wm + i * 16 + l15) * 32 + lq * 8];
      bh[i] = *(const bf16x8*)&Bh[(wn + i * 16 + l15) * 32 + lq * 8];
    }
#pragma unroll
    for (int i = 0; i < 4; ++i)
#pragma unroll
      for (int j = 0; j < 4; ++j) acc[i][j] = MFMA16(ah[i], bh[j], acc[i][j]);
  }
#pragma unroll
  for (int i = 0; i < 4; ++i)
#pragma unroll
    for (int j = 0; j < 4; ++j) {
      int colw = n0 + wn + j * 16 + l15;
#pragma unroll
      for (int r = 0; r < 4; ++r) {
        int rowg = bm * 128 + wm + i * 16 + lq * 4 + r;
        out[(size_t)rowg * 1024 + colw] = acc[i][j][r];
      }
    }
}

// ---------------- launch ----------------
extern "C" void kernel_launch(void* const* d_in, const int* in_sizes, int n_in,
                              void* d_out, int out_size, void* d_ws, size_t ws_size,
                              hipStream_t stream) {
  const float* hs = (const float*)d_in[0];
  const float* freqs = (const float*)d_in[1];
  const float* Wq = (const float*)d_in[2];
  const float* Wk = (const float*)d_in[3];
  const float* Wv = (const float*)d_in[4];
  const float* Wo = (const float*)d_in[5];
  float* out = (float*)d_out;

  const size_t MD = (size_t)4096 * 1024;
  const size_t WW = (size_t)1024 * 1024;
  unsigned short* hsH = (unsigned short*)d_ws;   // 8MB; reused as attnB
  unsigned short* WtqH = hsH + MD;
  unsigned short* WtkH = WtqH + WW;
  unsigned short* WtvH = WtkH + WW;
  unsigned short* WtoH = WtvH + WW;
  unsigned short* qB = WtoH + WW;
  unsigned short* kB = qB + MD;
  unsigned short* vB = kB + MD;
  unsigned short* cP = vB + MD;                  // 4 x 8MB partials
  float* rsW = (float*)(cP + 4 * MD);            // 1MB rowsums
  unsigned short* attnB = hsH;  // hs bf16 dead after k_qkv

  k_split<<<4096, 256, 0, stream>>>(hs, hsH, (int)(MD / 4));
  k_wsplit<<<dim3(32, 32, 4), 256, 0, stream>>>(Wq, Wk, Wv, Wo,
                                                WtqH, WtkH, WtvH, WtoH);
  k_qkv<<<dim3(24, 32), 256, 0, stream>>>(hsH, WtqH, WtkH, WtvH, freqs, qB, kB, vB);
  k_attn<<<dim3(8, 32, 4), 256, 0, stream>>>(qB, kB, vB, cP, rsW);
  k_comb<<<2048, 256, 0, stream>>>(cP, rsW, attnB, (int)(MD / 8));
  k_out<<<dim3(8, 32), 256, 0, stream>>>(attnB, WtoH, out);
}

// Round 8
// 258.656 us; speedup vs baseline: 1.2916x; 1.2916x over previous
//
#include <hip/hip_runtime.h>
#include <hip/hip_bf16.h>
#include <cstdint>

typedef __bf16 bf16x8 __attribute__((ext_vector_type(8)));
typedef float f32x4 __attribute__((ext_vector_type(4)));
typedef float f32x16 __attribute__((ext_vector_type(16)));

#define MFMA16(a, b, c) __builtin_amdgcn_mfma_f32_16x16x32_bf16(a, b, c, 0, 0, 0)
#define MFMA32(a, b, c) __builtin_amdgcn_mfma_f32_32x32x16_bf16(a, b, c, 0, 0, 0)

__device__ __forceinline__ void gload_lds16(const void* g, void* l) {
  __builtin_amdgcn_global_load_lds(
      (const __attribute__((address_space(1))) unsigned int*)g,
      (__attribute__((address_space(3))) unsigned int*)l, 16, 0, 0);
}

__device__ __forceinline__ unsigned short f2bf(float x) {
  union { float f; uint32_t u; } v; v.f = x;
  uint32_t r = v.u + 0x7fff + ((v.u >> 16) & 1);
  return (unsigned short)(r >> 16);
}
__device__ __forceinline__ float bf2f(unsigned short h) {
  union { float f; uint32_t u; } v; v.u = ((uint32_t)h) << 16;
  return v.f;
}
__device__ __forceinline__ f32x16 fzero16() {
  f32x16 v;
#pragma unroll
  for (int i = 0; i < 16; ++i) v[i] = 0.f;
  return v;
}

// ---------------- K1a: hidden_states -> bf16 ----------------
__global__ __launch_bounds__(256) void k_split(const float* __restrict__ x,
                                               unsigned short* __restrict__ hi, int n4) {
  int i = blockIdx.x * blockDim.x + threadIdx.x;
  if (i >= n4) return;
  float4 v = ((const float4*)x)[i];
  ushort4 h;
  h.x = f2bf(v.x); h.y = f2bf(v.y); h.z = f2bf(v.z); h.w = f2bf(v.w);
  ((ushort4*)hi)[i] = h;
}

// ------------ K1b: transpose weights -> bf16 (fused, z selects W) ------------
__global__ __launch_bounds__(256) void k_wsplit(
    const float* __restrict__ Wq, const float* __restrict__ Wk,
    const float* __restrict__ Wv, const float* __restrict__ Wo,
    unsigned short* __restrict__ WtqH, unsigned short* __restrict__ WtkH,
    unsigned short* __restrict__ WtvH, unsigned short* __restrict__ WtoH) {
  const int z = blockIdx.z;
  const float* W = (z == 0) ? Wq : (z == 1) ? Wk : (z == 2) ? Wv : Wo;
  unsigned short* WtH = (z == 0) ? WtqH : (z == 1) ? WtkH : (z == 2) ? WtvH : WtoH;
  __shared__ float tile[32][33];
  const int bx = blockIdx.x, by = blockIdx.y;
  const int tx = threadIdx.x & 31, ty = threadIdx.x >> 5;
#pragma unroll
  for (int i = 0; i < 4; ++i)
    tile[ty + i * 8][tx] = W[(size_t)(by * 32 + ty + i * 8) * 1024 + bx * 32 + tx];
  __syncthreads();
#pragma unroll
  for (int i = 0; i < 4; ++i) {
    float v = tile[tx][ty + i * 8];
    WtH[(size_t)(bx * 32 + ty + i * 8) * 1024 + by * 32 + tx] = f2bf(v);
  }
}

// ---------------- K2: QKV GEMM, plain bf16, global_load_lds staging ----------------
__global__ __launch_bounds__(256, 2) void k_qkv(
    const unsigned short* __restrict__ hsH,
    const unsigned short* __restrict__ WqH, const unsigned short* __restrict__ WkH,
    const unsigned short* __restrict__ WvH, const float* __restrict__ freqs,
    unsigned short* __restrict__ qB, unsigned short* __restrict__ kB,
    unsigned short* __restrict__ vB) {
  __shared__ unsigned short Ah[128 * 32], Bh[128 * 32];  // 8KB each, 64B rows
  const int tid = threadIdx.x;
  const int bm = blockIdx.y, bn = blockIdx.x;
  const int w = bn >> 3;           // 0=q 1=k 2=v
  const int n0 = (bn & 7) * 128;
  const unsigned short* WH = (w == 0) ? WqH : (w == 1) ? WkH : WvH;
  const int lane = tid & 63, wave = tid >> 6;
  const int wm = (wave & 1) * 64, wn = (wave >> 1) * 64;
  const int l15 = lane & 15, lq = lane >> 4;

  f32x4 acc[4][4];
#pragma unroll
  for (int i = 0; i < 4; i++)
#pragma unroll
    for (int j = 0; j < 4; j++) acc[i][j] = (f32x4){0.f, 0.f, 0.f, 0.f};

  const char* baseA = (const char*)hsH + (size_t)(bm * 128) * 2048;
  const char* baseB = (const char*)WH + (size_t)n0 * 2048;
  const int off0 = tid << 4, row0 = off0 >> 6, seg0 = off0 & 63;
  const int off1 = (tid + 256) << 4, row1 = off1 >> 6, seg1 = off1 & 63;

  for (int k0 = 0; k0 < 1024; k0 += 32) {
    __syncthreads();
    gload_lds16(baseA + (size_t)row0 * 2048 + k0 * 2 + seg0, (char*)Ah + wave * 1024);
    gload_lds16(baseB + (size_t)row0 * 2048 + k0 * 2 + seg0, (char*)Bh + wave * 1024);
    gload_lds16(baseA + (size_t)row1 * 2048 + k0 * 2 + seg1,
                (char*)Ah + 4096 + wave * 1024);
    gload_lds16(baseB + (size_t)row1 * 2048 + k0 * 2 + seg1,
                (char*)Bh + 4096 + wave * 1024);
    __syncthreads();
    bf16x8 ah[4], bh[4];
#pragma unroll
    for (int i = 0; i < 4; ++i) {
      ah[i] = *(const bf16x8*)&Ah[(wm + i * 16 + l15) * 32 + lq * 8];
      bh[i] = *(const bf16x8*)&Bh[(wn + i * 16 + l15) * 32 + lq * 8];
    }
#pragma unroll
    for (int i = 0; i < 4; ++i)
#pragma unroll
      for (int j = 0; j < 4; ++j) acc[i][j] = MFMA16(ah[i], bh[j], acc[i][j]);
  }

  // epilogue: C/D layout col=lane&15, row=(lane>>4)*4+r. RoPE for q,k. V transposed.
  unsigned short* dst = (w == 0) ? qB : (w == 1) ? kB : vB;
#pragma unroll
  for (int i = 0; i < 4; ++i) {
#pragma unroll
    for (int j = 0; j < 4; ++j) {
      int colw = n0 + wn + j * 16 + l15;
      int h = colw >> 6, d = colw & 63;
#pragma unroll
      for (int r = 0; r < 4; ++r) {
        int rowg = bm * 128 + wm + i * 16 + lq * 4 + r;
        int s = rowg & 2047, b = rowg >> 11;
        float val = acc[i][j][r];
        if (w < 2) {
          float partner = __shfl_xor(val, 1);
          int jj = d >> 1;
          float cs = freqs[(s * 32 + jj) * 2 + 0];
          float sn = freqs[(s * 32 + jj) * 2 + 1];
          float res = (d & 1) ? (partner * sn + val * cs) : (val * cs - partner * sn);
          dst[(((size_t)(b * 16 + h)) * 2048 + s) * 64 + d] = f2bf(res);
        } else {
          dst[(((size_t)(b * 16 + h)) * 64 + d) * 2048 + s] = f2bf(val);  // vB[bh][d][s]
        }
      }
    }
  }
}

// ------- K3: chunked attention (R6 structure) + K-prefetch + XCD swizzle -------
// 1D grid of 512; id = xcd + 8*(x + 8*hi), group g=(bh,chunk)=xcd+8*hi so all 8
// q-tile blocks of a (bh,chunk) share ids mod 8 -> same XCD -> K/V L2 reuse.
// kfa/kfb registers rotate: after S-MFMAs consume iter kb's K, the same regs are
// refilled for kb+1, giving the loads a full iteration to land (latency hiding).
#define LDP 72  // 144B rows: 16B-aligned b128 reads

__global__ __launch_bounds__(256, 2) void k_attn(
    const unsigned short* __restrict__ qB, const unsigned short* __restrict__ kB,
    const unsigned short* __restrict__ vB,
    unsigned short* __restrict__ c0, unsigned short* __restrict__ c1) {
  __shared__ unsigned short Pt[4 * 64 * LDP];  // 36.9 KB, wave-private regions
  const int tid = threadIdx.x, lane = tid & 63, wave = tid >> 6;
  const int l31 = lane & 31, lh = lane >> 5;
  const int bid = blockIdx.x;
  const int x = (bid >> 3) & 7;
  const int gg = (bid & 7) + 8 * (bid >> 6);
  const int bh = gg & 31;
  const int chunk = gg >> 5;
  const int q0 = x * 256 + wave * 64;
  const size_t base = (size_t)bh * 2048 * 64;
  const float sc = 0.125f * 1.44269504089f;  // scale * log2(e)

  // Q B-frags: lane n=l31 -> query q0+qt*32+l31, k=ks*16+lh*8
  bf16x8 qf[2][4];
#pragma unroll
  for (int qt = 0; qt < 2; ++qt)
#pragma unroll
    for (int ks = 0; ks < 4; ++ks)
      qf[qt][ks] = *(const bf16x8*)(qB + base + (size_t)(q0 + qt * 32 + l31) * 64 +
                                    ks * 16 + lh * 8);

  const unsigned short* kp = kB + base + (size_t)chunk * 1024 * 64 + l31 * 64 + lh * 8;
  const unsigned short* vp = vB + base + l31 * 2048 + chunk * 1024 + lh * 8;
  unsigned short* Pw = Pt + wave * (64 * LDP);

  // preload K for kb=0 (both 32-key halves)
  bf16x8 kfa[4], kfb[4];
#pragma unroll
  for (int ks = 0; ks < 4; ++ks) {
    kfa[ks] = *(const bf16x8*)(kp + ks * 16);
    kfb[ks] = *(const bf16x8*)(kp + 2048 + ks * 16);
  }
  kp += 4096;

  f32x16 o[2][2];  // [dt][qt]
#pragma unroll
  for (int a = 0; a < 2; ++a)
#pragma unroll
    for (int bq = 0; bq < 2; ++bq) o[a][bq] = fzero16();
  float rsum[2] = {0.f, 0.f};

  for (int kb = 0; kb < 16; ++kb) {
    // V^T frags up-front (consumed at iter end -> full S/exp phase to land)
    bf16x8 vf[2][4];
#pragma unroll
    for (int dt = 0; dt < 2; ++dt)
#pragma unroll
      for (int ks = 0; ks < 4; ++ks)
        vf[dt][ks] = *(const bf16x8*)(vp + dt * 65536 + ks * 16);

#pragma unroll
    for (int mt = 0; mt < 2; ++mt) {
      f32x16 s0 = fzero16(), s1 = fzero16();
      if (mt == 0) {
#pragma unroll
        for (int ks = 0; ks < 4; ++ks) {
          s0 = MFMA32(kfa[ks], qf[0][ks], s0);
          s1 = MFMA32(kfa[ks], qf[1][ks], s1);
        }
        // prefetch kb+1 first half into kfa (regs now consumed)
#pragma unroll
        for (int ks = 0; ks < 4; ++ks) kfa[ks] = *(const bf16x8*)(kp + ks * 16);
      } else {
#pragma unroll
        for (int ks = 0; ks < 4; ++ks) {
          s0 = MFMA32(kfb[ks], qf[0][ks], s0);
          s1 = MFMA32(kfb[ks], qf[1][ks], s1);
        }
        // prefetch kb+1 second half into kfb
#pragma unroll
        for (int ks = 0; ks < 4; ++ks)
          kfb[ks] = *(const bf16x8*)(kp + 2048 + ks * 16);
      }
#pragma unroll
      for (int qt = 0; qt < 2; ++qt) {
        const f32x16& sv = qt ? s1 : s0;
        float ps[16];
        float rs = 0.f;
#pragma unroll
        for (int r = 0; r < 16; ++r) {
          ps[r] = __builtin_exp2f(sv[r] * sc);
          rs += ps[r];
        }
        rsum[qt] += rs;
        unsigned int* prow =
            (unsigned int*)(Pw + (qt * 32 + l31) * LDP + mt * 32 + 4 * lh);
#pragma unroll
        for (int p = 0; p < 8; ++p) {
          union { unsigned int u; __bf16 h2[2]; } pk;
          pk.h2[0] = (__bf16)ps[2 * p];
          pk.h2[1] = (__bf16)ps[2 * p + 1];
          prow[4 * (p >> 1) + (p & 1)] = pk.u;
        }
      }
    }
    kp += 4096;  // 64 keys * 64 elems

    // O^T += V^T . P^T
#pragma unroll
    for (int qt = 0; qt < 2; ++qt)
#pragma unroll
      for (int ks = 0; ks < 4; ++ks) {
        bf16x8 pf = *(const bf16x8*)(Pw + (qt * 32 + l31) * LDP + ks * 16 + lh * 8);
        o[0][qt] = MFMA32(vf[0][ks], pf, o[0][qt]);
        o[1][qt] = MFMA32(vf[1][ks], pf, o[1][qt]);
      }
    vp += 64;  // 64 keys
  }

  // normalize + write bf16 chunk partial. O^T: d=dt*32+4*lh+8*g+t, q=qt*32+l31
  unsigned short* cB = chunk ? c1 : c0;
  const int b = bh >> 4, h = bh & 15;
#pragma unroll
  for (int qt = 0; qt < 2; ++qt) {
    float lsum = rsum[qt] + __shfl_xor(rsum[qt], 32);
    float inv = 1.f / lsum;
    int s = q0 + qt * 32 + l31;
#pragma unroll
    for (int dt = 0; dt < 2; ++dt)
#pragma unroll
      for (int g = 0; g < 4; ++g) {
        int d = dt * 32 + 4 * lh + 8 * g;
        size_t idx = ((size_t)(b * 2048 + s)) * 1024 + h * 64 + d;
        ushort4 hv;
#pragma unroll
        for (int t = 0; t < 4; ++t)
          ((unsigned short*)&hv)[t] = f2bf(o[dt][qt][g * 4 + t] * inv);
        *(ushort4*)(cB + idx) = hv;
      }
  }
}

// ---------------- K3b: combine chunk partials: attnB = bf16(c0 + c1) ----------------
__global__ __launch_bounds__(256) void k_comb(const unsigned short* __restrict__ c0,
                                              const unsigned short* __restrict__ c1,
                                              unsigned short* __restrict__ outB,
                                              int n8) {
  int i = blockIdx.x * blockDim.x + threadIdx.x;
  if (i >= n8) return;
  uint4 a = ((const uint4*)c0)[i];
  uint4 b = ((const uint4*)c1)[i];
  uint4 r;
  const unsigned short* pa = (const unsigned short*)&a;
  const unsigned short* pb = (const unsigned short*)&b;
  unsigned short* pr = (unsigned short*)&r;
#pragma unroll
  for (int j = 0; j < 8; ++j) pr[j] = f2bf(bf2f(pa[j]) + bf2f(pb[j]));
  ((uint4*)outB)[i] = r;
}

// ---------------- K4: output projection, plain bf16, fp32 store ----------------
__global__ __launch_bounds__(256, 2) void k_out(const unsigned short* __restrict__ A,
                                                const unsigned short* __restrict__ B,
                                                float* __restrict__ out) {
  __shared__ unsigned short Ah[128 * 32], Bh[128 * 32];
  const int tid = threadIdx.x;
  const int bm = blockIdx.y, n0 = blockIdx.x * 128;
  const int lane = tid & 63, wave = tid >> 6;
  const int wm = (wave & 1) * 64, wn = (wave >> 1) * 64;
  const int l15 = lane & 15, lq = lane >> 4;

  f32x4 acc[4][4];
#pragma unroll
  for (int i = 0; i < 4; i++)
#pragma unroll
    for (int j = 0; j < 4; j++) acc[i][j] = (f32x4){0.f, 0.f, 0.f, 0.f};

  const char* baseA = (const char*)A + (size_t)(bm * 128) * 2048;
  const char* baseB = (const char*)B + (size_t)n0 * 2048;
  const int off0 = tid << 4, row0 = off0 >> 6, seg0 = off0 & 63;
  const int off1 = (tid + 256) << 4, row1 = off1 >> 6, seg1 = off1 & 63;

  for (int k0 = 0; k0 < 1024; k0 += 32) {
    __syncthreads();
    gload_lds16(baseA + (size_t)row0 * 2048 + k0 * 2 + seg0, (char*)Ah + wave * 1024);
    gload_lds16(baseB + (size_t)row0 * 2048 + k0 * 2 + seg0, (char*)Bh + wave * 1024);
    gload_lds16(baseA + (size_t)row1 * 2048 + k0 * 2 + seg1,
                (char*)Ah + 4096 + wave * 1024);
    gload_lds16(baseB + (size_t)row1 * 2048 + k0 * 2 + seg1,
                (char*)Bh + 4096 + wave * 1024);
    __syncthreads();
    bf16x8 ah[4], bh[4];
#pragma unroll
    for (int i = 0; i < 4; ++i) {
      ah[i] = *(const bf16x8*)&Ah[(wm + i * 16 + l15) * 32 + lq * 8];
      bh[i] = *(const bf16x8*)&Bh[(wn + i * 16 + l15) * 32 + lq * 8];
    }
#pragma unroll
    for (int i = 0; i < 4; ++i)
#pragma unroll
      for (int j = 0; j < 4; ++j) acc[i][j] = MFMA16(ah[i], bh[j], acc[i][j]);
  }
#pragma unroll
  for (int i = 0; i < 4; ++i)
#pragma unroll
    for (int j = 0; j < 4; ++j) {
      int colw = n0 + wn + j * 16 + l15;
#pragma unroll
      for (int r = 0; r < 4; ++r) {
        int rowg = bm * 128 + wm + i * 16 + lq * 4 + r;
        out[(size_t)rowg * 1024 + colw] = acc[i][j][r];
      }
    }
}

// ---------------- launch ----------------
extern "C" void kernel_launch(void* const* d_in, const int* in_sizes, int n_in,
                              void* d_out, int out_size, void* d_ws, size_t ws_size,
                              hipStream_t stream) {
  const float* hs = (const float*)d_in[0];
  const float* freqs = (const float*)d_in[1];
  const float* Wq = (const float*)d_in[2];
  const float* Wk = (const float*)d_in[3];
  const float* Wv = (const float*)d_in[4];
  const float* Wo = (const float*)d_in[5];
  float* out = (float*)d_out;

  const size_t MD = (size_t)4096 * 1024;
  const size_t WW = (size_t)1024 * 1024;
  unsigned short* hsH = (unsigned short*)d_ws;   // 8MB; reused as attnB
  unsigned short* WtqH = hsH + MD;
  unsigned short* WtkH = WtqH + WW;
  unsigned short* WtvH = WtkH + WW;
  unsigned short* WtoH = WtvH + WW;
  unsigned short* qB = WtoH + WW;
  unsigned short* kB = qB + MD;
  unsigned short* vB = kB + MD;
  unsigned short* c0 = vB + MD;
  unsigned short* c1 = c0 + MD;
  unsigned short* attnB = hsH;  // hs bf16 dead after k_qkv

  k_split<<<4096, 256, 0, stream>>>(hs, hsH, (int)(MD / 4));
  k_wsplit<<<dim3(32, 32, 4), 256, 0, stream>>>(Wq, Wk, Wv, Wo,
                                                WtqH, WtkH, WtvH, WtoH);
  k_qkv<<<dim3(24, 32), 256, 0, stream>>>(hsH, WtqH, WtkH, WtvH, freqs, qB, kB, vB);
  k_attn<<<512, 256, 0, stream>>>(qB, kB, vB, c0, c1);
  k_comb<<<2048, 256, 0, stream>>>(c0, c1, attnB, (int)(MD / 8));
  k_out<<<dim3(8, 32), 256, 0, stream>>>(attnB, WtoH, out);
}